// Round 8
// baseline (888.052 us; speedup 1.0000x reference)
//
#include <hip/hip_runtime.h>

typedef _Float16 f16;
typedef _Float16 f16x8 __attribute__((ext_vector_type(8)));
typedef float f32x16 __attribute__((ext_vector_type(16)));

#define BK 64

__device__ __forceinline__ void async_cp16(const void* g, void* l) {
  __builtin_amdgcn_global_load_lds(
      (const __attribute__((address_space(1))) void*)g,
      (__attribute__((address_space(3))) void*)l, 16, 0, 0);
}

// ---------------------------------------------------------------------------
// L0 GEMM: 128x256 tile (R5-proven for fp32-A). TN=256 keeps the fp32
// descriptor re-read factor at N/TN=4 (R6: TN=128 doubled it, +50us).
// ---------------------------------------------------------------------------
__global__ __launch_bounds__(256, 2) void gemm_f16_l0(
    const float* __restrict__ Af32, const f16* __restrict__ Bt,
    const float* __restrict__ bias, f16* __restrict__ C, int M, int N,
    int K) {
  __shared__ alignas(16) f16 sA[128][BK];
  __shared__ alignas(16) f16 sB[256][BK];
  const int tid = threadIdx.x;
  const int lane = tid & 63;
  const int wave = tid >> 6;

  // XCD-aware remap (R0-proven for grid (4,512)).
  const int id = blockIdx.y * 4 + blockIdx.x;
  const int nt = (id >> 3) & 3;
  const int mt = (id & 7) * 64 + (id >> 5);
  const long long bm = (long long)mt * 128;
  const long long bn = (long long)nt * 256;

  const int wm = (wave & 1) * 64;
  const int wn = (wave >> 1) * 128;
  const int l31 = lane & 31;
  const int half = lane >> 5;

  const float* const A32base = Af32 + bm * (long long)K;
  const f16* const Bbase = Bt + bn * (long long)K;
  int aOff[4], bOff[8];
#pragma unroll
  for (int i = 0; i < 4; ++i) {
    const int chunk = wave * 256 + i * 64 + lane;
    const int ml = chunk >> 3;
    const int kc = (chunk & 7) ^ (ml & 7);
    aOff[i] = ml * K + kc * 8;
  }
#pragma unroll
  for (int i = 0; i < 8; ++i) {
    const int chunk = wave * 512 + i * 64 + lane;
    const int ml = chunk >> 3;
    const int kc = (chunk & 7) ^ (ml & 7);
    bOff[i] = ml * K + kc * 8;
  }

  f32x16 acc[2][4] = {};
  const int kIters = K / BK;
  for (int kt = 0; kt < kIters; ++kt) {
    const int k0 = kt * BK;
#pragma unroll
    for (int i = 0; i < 4; ++i) {
      float xv[8];
      *(float4*)(xv) = *(const float4*)(A32base + aOff[i] + k0);
      *(float4*)(xv + 4) = *(const float4*)(A32base + aOff[i] + k0 + 4);
      f16x8 o;
#pragma unroll
      for (int e = 0; e < 8; ++e) o[e] = (f16)xv[e];
      *(f16x8*)(&sA[0][0] + (wave * 256 + i * 64 + lane) * 8) = o;
    }
#pragma unroll
    for (int i = 0; i < 8; ++i)
      async_cp16(Bbase + bOff[i] + k0, &sB[0][0] + (wave * 512 + i * 64) * 8);
    __syncthreads();

#pragma unroll
    for (int s = 0; s < 4; ++s) {
      const int csw = ((s * 2 + half) ^ (lane & 7)) * 8;
      f16x8 af[2], bf[4];
#pragma unroll
      for (int i = 0; i < 2; ++i) af[i] = *(const f16x8*)&sA[wm + i * 32 + l31][csw];
#pragma unroll
      for (int j = 0; j < 4; ++j) bf[j] = *(const f16x8*)&sB[wn + j * 32 + l31][csw];
#pragma unroll
      for (int i = 0; i < 2; ++i)
#pragma unroll
        for (int j = 0; j < 4; ++j)
          acc[i][j] = __builtin_amdgcn_mfma_f32_32x32x16_f16(af[i], bf[j],
                                                             acc[i][j], 0, 0, 0);
    }
    __syncthreads();
  }

#pragma unroll
  for (int i = 0; i < 2; ++i)
#pragma unroll
    for (int j = 0; j < 4; ++j) {
      const long long colg = bn + wn + j * 32 + l31;
      const float bval = bias[colg];
#pragma unroll
      for (int reg = 0; reg < 16; ++reg) {
        const long long rowg =
            bm + wm + i * 32 + (reg & 3) + 8 * (reg >> 2) + 4 * half;
        C[rowg * N + colg] = (f16)fmaxf(acc[i][j][reg] + bval, 0.f);
      }
    }
}

// ---------------------------------------------------------------------------
// Hidden GEMM: 128x128 tile (R6/R7-measured 167 vs 172 at 128x256),
// 4 waves of 64x64 (2x2 of 32x32 accs). VGPR 56, LDS 32KB.
// launch_bounds(256,5): LDS allows 5 blocks/CU; R7 showed (256,4) left
// occupancy at 39% (~3 blocks) -- probe whether the bound or scheduler caps.
// ---------------------------------------------------------------------------
__global__ __launch_bounds__(256, 5) void gemm_f16_h(
    const f16* __restrict__ A, const f16* __restrict__ Bt,
    f16* __restrict__ C, int M, int N, int K) {
  __shared__ alignas(16) f16 sA[128][BK];
  __shared__ alignas(16) f16 sB[128][BK];
  const int tid = threadIdx.x;
  const int lane = tid & 63;
  const int wave = tid >> 6;

  // XCD-aware remap for grid (8,512): 8 consecutive same-XCD blocks share
  // one A-panel (256 KB) and cycle all 8 nt (full 2 MB B) -> 2.25 MB
  // working set per XCD L2. Bijective over [0,4096).
  const int id = blockIdx.y * 8 + blockIdx.x;
  const int nt = (id >> 3) & 7;
  const int mt = (id & 7) * 64 + (id >> 6);
  const long long bm = (long long)mt * 128;
  const long long bn = (long long)nt * 128;

  const int wm = (wave & 1) * 64;
  const int wn = (wave >> 1) * 64;
  const int l31 = lane & 31;
  const int half = lane >> 5;

  const f16* const Abase = A + bm * (long long)K;
  const f16* const Bbase = Bt + bn * (long long)K;
  int aOff[4];
#pragma unroll
  for (int i = 0; i < 4; ++i) {
    const int chunk = wave * 256 + i * 64 + lane;
    const int ml = chunk >> 3;
    const int kc = (chunk & 7) ^ (ml & 7);  // R2-verified XOR swizzle
    aOff[i] = ml * K + kc * 8;  // same geometry for A and B (128 x 64)
  }

  f32x16 acc[2][2] = {};
  const int kIters = K / BK;
  for (int kt = 0; kt < kIters; ++kt) {
    const int k0 = kt * BK;
#pragma unroll
    for (int i = 0; i < 4; ++i)
      async_cp16(Abase + aOff[i] + k0, &sA[0][0] + (wave * 256 + i * 64) * 8);
#pragma unroll
    for (int i = 0; i < 4; ++i)
      async_cp16(Bbase + aOff[i] + k0, &sB[0][0] + (wave * 256 + i * 64) * 8);
    __syncthreads();

#pragma unroll
    for (int s = 0; s < 4; ++s) {
      const int csw = ((s * 2 + half) ^ (lane & 7)) * 8;
      f16x8 af[2], bf[2];
#pragma unroll
      for (int i = 0; i < 2; ++i) af[i] = *(const f16x8*)&sA[wm + i * 32 + l31][csw];
#pragma unroll
      for (int j = 0; j < 2; ++j) bf[j] = *(const f16x8*)&sB[wn + j * 32 + l31][csw];
#pragma unroll
      for (int i = 0; i < 2; ++i)
#pragma unroll
        for (int j = 0; j < 2; ++j)
          acc[i][j] = __builtin_amdgcn_mfma_f32_32x32x16_f16(af[i], bf[j],
                                                             acc[i][j], 0, 0, 0);
    }
    __syncthreads();
  }

#pragma unroll
  for (int i = 0; i < 2; ++i)
#pragma unroll
    for (int j = 0; j < 2; ++j) {
      const long long colg = bn + wn + j * 32 + l31;
#pragma unroll
      for (int reg = 0; reg < 16; ++reg) {
        const long long rowg =
            bm + wm + i * 32 + (reg & 3) + 8 * (reg >> 2) + 4 * half;
        C[rowg * N + colg] = (f16)acc[i][j][reg];
      }
    }
}

// Grid-strided (G11): 2048 blocks x 4-row waves, 8 iterations each.
// LayerNorm(y) * g + b, relu, write f16. Body R2-proven.
__global__ __launch_bounds__(256) void ln_relu_kernel(
    const f16* __restrict__ Y, const float* __restrict__ g,
    const float* __restrict__ b, f16* __restrict__ H) {
  const int lane = threadIdx.x & 63;
  const int wave = threadIdx.x >> 6;
  for (int rb = blockIdx.x; rb < 16384; rb += 2048) {
    const long long row = (long long)rb * 4 + wave;
    const f16* y = Y + row * 1024;
    float x[16];
    float s1 = 0.f, s2 = 0.f;
#pragma unroll
    for (int p = 0; p < 2; ++p) {
      f16x8 v = *(const f16x8*)(y + p * 512 + lane * 8);
#pragma unroll
      for (int e = 0; e < 8; ++e) {
        const float f = (float)v[e];
        x[p * 8 + e] = f;
        s1 += f;
        s2 += f * f;
      }
    }
#pragma unroll
    for (int off = 32; off >= 1; off >>= 1) {
      s1 += __shfl_xor(s1, off);
      s2 += __shfl_xor(s2, off);
    }
    const float mean = s1 * (1.f / 1024.f);
    const float var = fmaxf(s2 * (1.f / 1024.f) - mean * mean, 0.f);
    const float inv = rsqrtf(var + 1e-6f);
    f16* h = H + row * 1024;
#pragma unroll
    for (int p = 0; p < 2; ++p) {
      f16x8 o;
#pragma unroll
      for (int e = 0; e < 8; ++e) {
        const int c = p * 512 + lane * 8 + e;
        const float v = (x[p * 8 + e] - mean) * inv * g[c] + b[c];
        o[e] = (f16)fmaxf(v, 0.f);
      }
      *(f16x8*)(h + p * 512 + lane * 8) = o;
    }
  }
}

// Grid-strided (G11) fused layer-3 LN + relu + output dot:
// out[row] = relu(dot(relu(LN(y)*g+b), Wout) + bout)
__global__ __launch_bounds__(256) void ln_relu_out_kernel(
    const f16* __restrict__ Y, const float* __restrict__ g,
    const float* __restrict__ b, const float* __restrict__ Wout,
    const float* __restrict__ bout, float* __restrict__ out) {
  const int lane = threadIdx.x & 63;
  const int wave = threadIdx.x >> 6;
  for (int rb = blockIdx.x; rb < 16384; rb += 2048) {
    const long long row = (long long)rb * 4 + wave;
    const f16* y = Y + row * 1024;
    float x[16];
    float s1 = 0.f, s2 = 0.f;
#pragma unroll
    for (int p = 0; p < 2; ++p) {
      f16x8 v = *(const f16x8*)(y + p * 512 + lane * 8);
#pragma unroll
      for (int e = 0; e < 8; ++e) {
        const float f = (float)v[e];
        x[p * 8 + e] = f;
        s1 += f;
        s2 += f * f;
      }
    }
#pragma unroll
    for (int off = 32; off >= 1; off >>= 1) {
      s1 += __shfl_xor(s1, off);
      s2 += __shfl_xor(s2, off);
    }
    const float mean = s1 * (1.f / 1024.f);
    const float var = fmaxf(s2 * (1.f / 1024.f) - mean * mean, 0.f);
    const float inv = rsqrtf(var + 1e-6f);
    float dot = 0.f;
#pragma unroll
    for (int p = 0; p < 2; ++p) {
#pragma unroll
      for (int e = 0; e < 8; ++e) {
        const int c = p * 512 + lane * 8 + e;
        const float v = fmaxf((x[p * 8 + e] - mean) * inv * g[c] + b[c], 0.f);
        dot += v * Wout[c];
      }
    }
#pragma unroll
    for (int off = 32; off >= 1; off >>= 1) dot += __shfl_xor(dot, off);
    if (lane == 0) out[row] = fmaxf(dot + bout[0], 0.f);
  }
}

// All 4 weight transposes in ONE launch. z selects the matrix.
__global__ __launch_bounds__(256) void transpose_cvt_all(
    const float* __restrict__ W0, const float* __restrict__ W1,
    const float* __restrict__ W2, const float* __restrict__ W3,
    f16* __restrict__ Wt0, f16* __restrict__ Wt1, f16* __restrict__ Wt2,
    f16* __restrict__ Wt3) {
  const int z = blockIdx.z;
  const float* W = z == 0 ? W0 : (z == 1 ? W1 : (z == 2 ? W2 : W3));
  f16* Wt = z == 0 ? Wt0 : (z == 1 ? Wt1 : (z == 2 ? Wt2 : Wt3));
  const int K = z == 0 ? 512 : 1024;
  const int N = 1024;
  const int bk = blockIdx.y * 64;
  if (bk >= K) return;
  __shared__ float tile[64][65];
  const int bn = blockIdx.x * 64;
  const int tx = threadIdx.x & 63;
  const int ty = threadIdx.x >> 6;  // 0..3
#pragma unroll
  for (int i = 0; i < 64; i += 4)
    tile[ty + i][tx] = W[(long long)(bk + ty + i) * N + bn + tx];
  __syncthreads();
#pragma unroll
  for (int i = 0; i < 64; i += 4)
    Wt[(long long)(bn + ty + i) * K + bk + tx] = (f16)tile[tx][ty + i];
}

extern "C" void kernel_launch(void* const* d_in, const int* in_sizes, int n_in,
                              void* d_out, int out_size, void* d_ws, size_t ws_size,
                              hipStream_t stream) {
  const float* desc = (const float*)d_in[0];
  const float* W0 = (const float*)d_in[1];
  const float* b0 = (const float*)d_in[2];
  const float* W1 = (const float*)d_in[3];
  const float* g1 = (const float*)d_in[4];
  const float* be1 = (const float*)d_in[5];
  const float* W2 = (const float*)d_in[6];
  const float* g2 = (const float*)d_in[7];
  const float* be2 = (const float*)d_in[8];
  const float* W3 = (const float*)d_in[9];
  const float* g3 = (const float*)d_in[10];
  const float* be3 = (const float*)d_in[11];
  const float* Wout = (const float*)d_in[12];
  const float* bout = (const float*)d_in[13];
  float* out = (float*)d_out;

  const long long Nrows = 65536, D = 512, W = 1024;
  char* p = (char*)d_ws;
  f16* Wt0 = (f16*)p;   p += D * W * sizeof(f16);       // 1 MB
  f16* Wt1 = (f16*)p;   p += W * W * sizeof(f16);       // 2 MB
  f16* Wt2 = (f16*)p;   p += W * W * sizeof(f16);       // 2 MB
  f16* Wt3 = (f16*)p;   p += W * W * sizeof(f16);       // 2 MB
  f16* H = (f16*)p;     p += Nrows * W * sizeof(f16);   // 134.2 MB
  f16* Y = (f16*)p;     p += Nrows * W * sizeof(f16);   // 134.2 MB
  (void)ws_size; (void)in_sizes; (void)n_in; (void)out_size;

  transpose_cvt_all<<<dim3(16, 16, 4), 256, 0, stream>>>(W0, W1, W2, W3, Wt0,
                                                         Wt1, Wt2, Wt3);

  dim3 g0(4, 512);   // L0: 128x256 tiles
  dim3 gh(8, 512);   // hidden: 128x128 tiles

  // L0: relu(desc @ W0 + b0) -> H   (fp32 cvt fused into A-staging)
  gemm_f16_l0<<<g0, 256, 0, stream>>>(desc, Wt0, b0, H, (int)Nrows, (int)W,
                                      (int)D);

  // L1: H @ W1 -> Y
  gemm_f16_h<<<gh, 256, 0, stream>>>(H, Wt1, Y, (int)Nrows, (int)W, (int)W);
  ln_relu_kernel<<<2048, 256, 0, stream>>>(Y, g1, be1, H);

  // L2
  gemm_f16_h<<<gh, 256, 0, stream>>>(H, Wt2, Y, (int)Nrows, (int)W, (int)W);
  ln_relu_kernel<<<2048, 256, 0, stream>>>(Y, g2, be2, H);

  // L3
  gemm_f16_h<<<gh, 256, 0, stream>>>(H, Wt3, Y, (int)Nrows, (int)W, (int)W);

  // out = relu(relu(LN3(Y)) @ Wout + bout)
  ln_relu_out_kernel<<<2048, 256, 0, stream>>>(Y, g3, be3, Wout, bout, out);
}

// Round 10
// 862.156 us; speedup vs baseline: 1.0300x; 1.0300x over previous
//
#include <hip/hip_runtime.h>

typedef _Float16 f16;
typedef _Float16 f16x8 __attribute__((ext_vector_type(8)));
typedef float f32x16 __attribute__((ext_vector_type(16)));

#define TM 128   // block M tile
#define TN 256   // block N tile
#define BK 64

__device__ __forceinline__ void async_cp16(const void* g, void* l) {
  __builtin_amdgcn_global_load_lds(
      (const __attribute__((address_space(1))) void*)g,
      (__attribute__((address_space(3))) void*)l, 16, 0, 0);
}

// C = A @ Bt^T, A [M][K] f16/f32, Bt [N][K] f16 row-major.
// Block 128x256, 4 waves of 64x128 (2x4 of 32x32 MFMA accs). R0/R3/R5-
// proven best TOTAL config (851/864 us, n=2). Measured-closed levers on
// this problem: 8-phase 256^2 (R1: 1 blk/CU loses inter-block overlap at
// nT=16), LN-in-A-staging (R2: serial reg-staging latency), cooperative
// mega-kernel (R4: lockstep phases + fence L2 flush halved every pipe),
// hidden-GEMM 128^2 tile (R6-R8: wins 5us/kernel, loses 25+us in total
// via 2x workgroup dispatch ramp at GEMM->LN boundaries), occupancy
// bounds probes (R7/R8: cap is not the declared bound), grid-strided LN
// (R8: null). This is the plateau of this structure on this shape.
// LNA: 0 = A f16 via global_load_lds (async, fastest); 2 = A fp32,
//      reg-staged cvt (R2-measured ~free for GEMM0).
// NOTE: SQ_LDS_BANK_CONFLICT saturates at 2^24 -- do not trust it.
template <int LNA, int EPI>
__global__ __launch_bounds__(256, 2) void gemm_f16(
    const f16* __restrict__ Af16, const float* __restrict__ Af32,
    const f16* __restrict__ Bt, const float* __restrict__ bias,
    f16* __restrict__ C, int M, int N, int K) {
  __shared__ alignas(16) f16 sA[TM][BK];
  __shared__ alignas(16) f16 sB[TN][BK];
  const int tid = threadIdx.x;
  const int lane = tid & 63;
  const int wave = tid >> 6;

  // XCD-aware remap: the 4 blocks sharing an A-panel (same mt) get ids
  // spaced 8 apart -> same XCD under round-robin dispatch -> panel stays
  // in that XCD's L2. (R2-verified mechanism: FETCH 530 -> 112 MB.)
  int mt, nt;
  if (gridDim.x == 4 && gridDim.y == 512) {
    const int id = blockIdx.y * 4 + blockIdx.x;
    nt = (id >> 3) & 3;
    mt = (id & 7) * 64 + (id >> 5);
  } else {
    nt = blockIdx.x;
    mt = blockIdx.y;
  }
  const long long bm = (long long)mt * TM;
  const long long bn = (long long)nt * TN;

  const int wm = (wave & 1) * 64;    // wave's 64-row band
  const int wn = (wave >> 1) * 128;  // wave's 128-col band
  const int l31 = lane & 31;
  const int half = lane >> 5;

  // Block-uniform bases (SGPR) + 32-bit lane-dependent element offsets.
  const f16* const Abase = Af16 + bm * (long long)K;
  const float* const A32base = Af32 ? (Af32 + bm * (long long)K) : nullptr;
  const f16* const Bbase = Bt + bn * (long long)K;
  int aOff[4], bOff[8];
#pragma unroll
  for (int i = 0; i < 4; ++i) {
    const int chunk = wave * 256 + i * 64 + lane;
    const int ml = chunk >> 3;
    const int kc = (chunk & 7) ^ (ml & 7);  // R2-verified XOR swizzle
    aOff[i] = ml * K + kc * 8;
  }
#pragma unroll
  for (int i = 0; i < 8; ++i) {
    const int chunk = wave * 512 + i * 64 + lane;
    const int ml = chunk >> 3;
    const int kc = (chunk & 7) ^ (ml & 7);
    bOff[i] = ml * K + kc * 8;
  }

  f32x16 acc[2][4] = {};  // 2(m) x 4(n) of 32x32 tiles

  const int kIters = K / BK;
  for (int kt = 0; kt < kIters; ++kt) {
    const int k0 = kt * BK;
    if (LNA == 0) {
#pragma unroll
      for (int i = 0; i < 4; ++i)
        async_cp16(Abase + aOff[i] + k0, &sA[0][0] + (wave * 256 + i * 64) * 8);
    } else {  // LNA == 2: fp32 -> f16 cvt staging (GEMM0 only)
#pragma unroll
      for (int i = 0; i < 4; ++i) {
        float xv[8];
        *(float4*)(xv) = *(const float4*)(A32base + aOff[i] + k0);
        *(float4*)(xv + 4) = *(const float4*)(A32base + aOff[i] + k0 + 4);
        f16x8 o;
#pragma unroll
        for (int e = 0; e < 8; ++e) o[e] = (f16)xv[e];
        *(f16x8*)(&sA[0][0] + (wave * 256 + i * 64 + lane) * 8) = o;
      }
    }
#pragma unroll
    for (int i = 0; i < 8; ++i)
      async_cp16(Bbase + bOff[i] + k0, &sB[0][0] + (wave * 512 + i * 64) * 8);
    __syncthreads();

#pragma unroll
    for (int s = 0; s < 4; ++s) {  // K=16 per step
      // A-operand 32x32x16: m = lane&31, k = (lane>>5)*8 + j (B mirrors, n).
      const int csw = ((s * 2 + half) ^ (lane & 7)) * 8;
      f16x8 af[2], bf[4];
#pragma unroll
      for (int i = 0; i < 2; ++i) af[i] = *(const f16x8*)&sA[wm + i * 32 + l31][csw];
#pragma unroll
      for (int j = 0; j < 4; ++j) bf[j] = *(const f16x8*)&sB[wn + j * 32 + l31][csw];
#pragma unroll
      for (int i = 0; i < 2; ++i)
#pragma unroll
        for (int j = 0; j < 4; ++j)
          acc[i][j] = __builtin_amdgcn_mfma_f32_32x32x16_f16(af[i], bf[j],
                                                             acc[i][j], 0, 0, 0);
    }
    __syncthreads();
  }

  // Epilogue. 32x32 C/D: col = lane&31, row = (reg&3) + 8*(reg>>2) + 4*(lane>>5)
#pragma unroll
  for (int i = 0; i < 2; ++i)
#pragma unroll
    for (int j = 0; j < 4; ++j) {
      const long long colg = bn + wn + j * 32 + l31;
      float bval = 0.f;
      if (EPI == 0) bval = bias[colg];
#pragma unroll
      for (int reg = 0; reg < 16; ++reg) {
        const long long rowg =
            bm + wm + i * 32 + (reg & 3) + 8 * (reg >> 2) + 4 * half;
        float v = acc[i][j][reg];
        if (EPI == 0) v = fmaxf(v + bval, 0.f);
        C[rowg * N + colg] = (f16)v;
      }
    }
}

// One wave per row: LayerNorm(y) * g + b, relu, write f16. (R2-proven.)
__global__ __launch_bounds__(256) void ln_relu_kernel(
    const f16* __restrict__ Y, const float* __restrict__ g,
    const float* __restrict__ b, f16* __restrict__ H) {
  const int lane = threadIdx.x & 63;
  const int wave = threadIdx.x >> 6;
  const long long row = (long long)blockIdx.x * 4 + wave;
  const f16* y = Y + row * 1024;
  float x[16];
  float s1 = 0.f, s2 = 0.f;
#pragma unroll
  for (int p = 0; p < 2; ++p) {
    f16x8 v = *(const f16x8*)(y + p * 512 + lane * 8);
#pragma unroll
    for (int e = 0; e < 8; ++e) {
      const float f = (float)v[e];
      x[p * 8 + e] = f;
      s1 += f;
      s2 += f * f;
    }
  }
#pragma unroll
  for (int off = 32; off >= 1; off >>= 1) {
    s1 += __shfl_xor(s1, off);
    s2 += __shfl_xor(s2, off);
  }
  const float mean = s1 * (1.f / 1024.f);
  const float var = fmaxf(s2 * (1.f / 1024.f) - mean * mean, 0.f);
  const float inv = rsqrtf(var + 1e-6f);
  f16* h = H + row * 1024;
#pragma unroll
  for (int p = 0; p < 2; ++p) {
    f16x8 o;
#pragma unroll
    for (int e = 0; e < 8; ++e) {
      const int c = p * 512 + lane * 8 + e;
      const float v = (x[p * 8 + e] - mean) * inv * g[c] + b[c];
      o[e] = (f16)fmaxf(v, 0.f);
    }
    *(f16x8*)(h + p * 512 + lane * 8) = o;
  }
}

// Fused layer-3 LN + relu + output dot (R2-proven):
// out[row] = relu(dot(relu(LN(y)*g+b), Wout) + bout)
__global__ __launch_bounds__(256) void ln_relu_out_kernel(
    const f16* __restrict__ Y, const float* __restrict__ g,
    const float* __restrict__ b, const float* __restrict__ Wout,
    const float* __restrict__ bout, float* __restrict__ out) {
  const int lane = threadIdx.x & 63;
  const int wave = threadIdx.x >> 6;
  const long long row = (long long)blockIdx.x * 4 + wave;
  const f16* y = Y + row * 1024;
  float x[16];
  float s1 = 0.f, s2 = 0.f;
#pragma unroll
  for (int p = 0; p < 2; ++p) {
    f16x8 v = *(const f16x8*)(y + p * 512 + lane * 8);
#pragma unroll
    for (int e = 0; e < 8; ++e) {
      const float f = (float)v[e];
      x[p * 8 + e] = f;
      s1 += f;
      s2 += f * f;
    }
  }
#pragma unroll
  for (int off = 32; off >= 1; off >>= 1) {
    s1 += __shfl_xor(s1, off);
    s2 += __shfl_xor(s2, off);
  }
  const float mean = s1 * (1.f / 1024.f);
  const float var = fmaxf(s2 * (1.f / 1024.f) - mean * mean, 0.f);
  const float inv = rsqrtf(var + 1e-6f);
  float dot = 0.f;
#pragma unroll
  for (int p = 0; p < 2; ++p) {
#pragma unroll
    for (int e = 0; e < 8; ++e) {
      const int c = p * 512 + lane * 8 + e;
      const float v = fmaxf((x[p * 8 + e] - mean) * inv * g[c] + b[c], 0.f);
      dot += v * Wout[c];
    }
  }
#pragma unroll
  for (int off = 32; off >= 1; off >>= 1) dot += __shfl_xor(dot, off);
  if (lane == 0) out[row] = fmaxf(dot + bout[0], 0.f);
}

// All 4 weight transposes in ONE launch. z selects the matrix.
// W [K][N] fp32 -> Wt [N][K] f16, 64x64 LDS tiles. N = 1024 for all;
// K = 512 for z=0 (half the y-tiles return early).
__global__ __launch_bounds__(256) void transpose_cvt_all(
    const float* __restrict__ W0, const float* __restrict__ W1,
    const float* __restrict__ W2, const float* __restrict__ W3,
    f16* __restrict__ Wt0, f16* __restrict__ Wt1, f16* __restrict__ Wt2,
    f16* __restrict__ Wt3) {
  const int z = blockIdx.z;
  const float* W = z == 0 ? W0 : (z == 1 ? W1 : (z == 2 ? W2 : W3));
  f16* Wt = z == 0 ? Wt0 : (z == 1 ? Wt1 : (z == 2 ? Wt2 : Wt3));
  const int K = z == 0 ? 512 : 1024;
  const int N = 1024;
  const int bk = blockIdx.y * 64;
  if (bk >= K) return;
  __shared__ float tile[64][65];
  const int bn = blockIdx.x * 64;
  const int tx = threadIdx.x & 63;
  const int ty = threadIdx.x >> 6;  // 0..3
#pragma unroll
  for (int i = 0; i < 64; i += 4)
    tile[ty + i][tx] = W[(long long)(bk + ty + i) * N + bn + tx];
  __syncthreads();
#pragma unroll
  for (int i = 0; i < 64; i += 4)
    Wt[(long long)(bn + ty + i) * K + bk + tx] = (f16)tile[tx][ty + i];
}

extern "C" void kernel_launch(void* const* d_in, const int* in_sizes, int n_in,
                              void* d_out, int out_size, void* d_ws, size_t ws_size,
                              hipStream_t stream) {
  const float* desc = (const float*)d_in[0];
  const float* W0 = (const float*)d_in[1];
  const float* b0 = (const float*)d_in[2];
  const float* W1 = (const float*)d_in[3];
  const float* g1 = (const float*)d_in[4];
  const float* be1 = (const float*)d_in[5];
  const float* W2 = (const float*)d_in[6];
  const float* g2 = (const float*)d_in[7];
  const float* be2 = (const float*)d_in[8];
  const float* W3 = (const float*)d_in[9];
  const float* g3 = (const float*)d_in[10];
  const float* be3 = (const float*)d_in[11];
  const float* Wout = (const float*)d_in[12];
  const float* bout = (const float*)d_in[13];
  float* out = (float*)d_out;

  const long long Nrows = 65536, D = 512, W = 1024;
  char* p = (char*)d_ws;
  f16* Wt0 = (f16*)p;   p += D * W * sizeof(f16);       // 1 MB
  f16* Wt1 = (f16*)p;   p += W * W * sizeof(f16);       // 2 MB
  f16* Wt2 = (f16*)p;   p += W * W * sizeof(f16);       // 2 MB
  f16* Wt3 = (f16*)p;   p += W * W * sizeof(f16);       // 2 MB
  f16* H = (f16*)p;     p += Nrows * W * sizeof(f16);   // 134.2 MB
  f16* Y = (f16*)p;     p += Nrows * W * sizeof(f16);   // 134.2 MB
  (void)ws_size; (void)in_sizes; (void)n_in; (void)out_size;

  transpose_cvt_all<<<dim3(16, 16, 4), 256, 0, stream>>>(W0, W1, W2, W3, Wt0,
                                                         Wt1, Wt2, Wt3);

  dim3 ggrid(W / TN, Nrows / TM);  // (4, 512)

  // L0: relu(desc @ W0 + b0) -> H   (fp32 cvt fused into A-staging)
  gemm_f16<2, 0><<<ggrid, 256, 0, stream>>>(nullptr, desc, Wt0, b0, H,
                                            (int)Nrows, (int)W, (int)D);

  // L1: H @ W1 -> Y
  gemm_f16<0, 1><<<ggrid, 256, 0, stream>>>(H, nullptr, Wt1, nullptr, Y,
                                            (int)Nrows, (int)W, (int)W);
  ln_relu_kernel<<<(int)(Nrows / 4), 256, 0, stream>>>(Y, g1, be1, H);

  // L2
  gemm_f16<0, 1><<<ggrid, 256, 0, stream>>>(H, nullptr, Wt2, nullptr, Y,
                                            (int)Nrows, (int)W, (int)W);
  ln_relu_kernel<<<(int)(Nrows / 4), 256, 0, stream>>>(Y, g2, be2, H);

  // L3
  gemm_f16<0, 1><<<ggrid, 256, 0, stream>>>(H, nullptr, Wt3, nullptr, Y,
                                            (int)Nrows, (int)W, (int)W);

  // out = relu(relu(LN3(Y)) @ Wout + bout)
  ln_relu_out_kernel<<<(int)(Nrows / 4), 256, 0, stream>>>(Y, g3, be3, Wout,
                                                           bout, out);
}